// Round 1
// baseline (275.614 us; speedup 1.0000x reference)
//
#include <hip/hip_runtime.h>
#include <math.h>

#define BB 8
#define NA 5
#define NC 8
#define NH 192
#define NW 192
#define TT 50
#define ATTRS 15
#define THRESH_F 0.6f

static const size_t FLAGS_N = (size_t)BB * NA * NH * NW;      // 1,474,560 bytes (u8)
#define ACC_OFF  FLAGS_N                                       // 8-byte aligned (1474560 % 8 == 0)
#define NACC 16
#define REC_OFF  (ACC_OFF + NACC * sizeof(double))

// acc indices: 0 n_obj, 1 sx, 2 sy, 3 sw, 4 sh, 5 s_bce_obj, 6 s_ce, 7 s_bce_noobj, 8 s_noobj

struct Rec {
    int cell;      // within-batch cell index: (a*NH + gj)*NW + gi
    int label;
    float tx, ty, tw, th;
    int valid;
    int pad;
};

__device__ __forceinline__ float sigmoidf_(float v) {
    return 1.0f / (1.0f + expf(-v));
}

// Phase A: one thread per batch, sequential over targets (preserves scatter order / last-wins).
__global__ void build_targets_k(const float* __restrict__ tgt,
                                const float* __restrict__ anchors,
                                unsigned char* __restrict__ flags,
                                Rec* __restrict__ recs) {
    int b = threadIdx.x;
    if (b >= BB) return;
    float aw[NA], ah[NA];
    for (int a = 0; a < NA; ++a) { aw[a] = anchors[2*a]; ah[a] = anchors[2*a+1]; }
    for (int t = 0; t < TT; ++t) {
        const float* p = tgt + ((size_t)b * TT + t) * 5;
        float lab = p[0], cx = p[1], cy = p[2], cw = p[3], ch = p[4];
        float s = lab + cx + cy + cw + ch;
        Rec r;
        r.valid = (s != 0.0f) ? 1 : 0;
        float gx = cx * NW, gy = cy * NH, gw = cw * NW, gh = ch * NH;
        int gi = (int)floorf(gx);
        int gj = (int)floorf(gy);
        gi = min(max(gi, 0), NW - 1);
        gj = min(max(gj, 0), NH - 1);
        float ious[NA];
        int best = 0; float bi = -1.0f;
        for (int a = 0; a < NA; ++a) {
            float inter = fminf(gw, aw[a]) * fminf(gh, ah[a]);
            float un = gw * gh + aw[a] * ah[a] - inter;
            float iou = inter / un;
            ious[a] = iou;
            if (iou > bi) { bi = iou; best = a; }   // first-max like jnp.argmax
        }
        if (r.valid) {
            // conf_mask zeroing: any anchor with iou > THRESH
            for (int a = 0; a < NA; ++a) {
                if (ious[a] > THRESH_F) {
                    size_t fi = (((size_t)b * NA + a) * NH + gj) * NW + gi;
                    flags[fi] |= 1u;   // exclusive b-slice per thread: plain RMW is safe
                }
            }
            // mask / conf_mask reset at best-anchor cell
            size_t fb = (((size_t)b * NA + best) * NH + gj) * NW + gi;
            flags[fb] |= 2u;
        }
        r.cell = (best * NH + gj) * NW + gi;
        r.label = (int)lab;
        r.tx = gx - floorf(gx);
        r.ty = gy - floorf(gy);
        r.tw = logf(gw / aw[best] + 1e-16f);
        r.th = logf(gh / ah[best] + 1e-16f);
        recs[b * TT + t] = r;
    }
}

// Phase B: per-target; winner = last valid target writing a given cell (JAX scatter last-wins).
__global__ void obj_losses_k(const float* __restrict__ x,
                             const Rec* __restrict__ recs,
                             double* __restrict__ acc) {
    int i = blockIdx.x * blockDim.x + threadIdx.x;
    if (i >= BB * TT) return;
    int b = i / TT, t = i % TT;
    Rec r = recs[i];
    if (!r.valid) return;
    for (int t2 = t + 1; t2 < TT; ++t2) {
        Rec r2 = recs[b * TT + t2];
        if (r2.valid && r2.cell == r.cell) return;   // superseded by later write
    }
    const size_t CH = (size_t)NH * NW;
    int a  = r.cell / (NH * NW);
    int hw = r.cell % (NH * NW);
    size_t base = ((size_t)(b * NA + a) * ATTRS) * CH + hw;
    float v0 = x[base + 0 * CH];
    float v1 = x[base + 1 * CH];
    float v2 = x[base + 2 * CH];
    float v3 = x[base + 3 * CH];
    float v6 = x[base + 6 * CH];
    float px = sigmoidf_(v0);
    float py = sigmoidf_(v1);
    float pconf = sigmoidf_(v6);
    pconf = fminf(fmaxf(pconf, 1e-7f), 1.0f - 1e-7f);
    float lx = (px - r.tx) * (px - r.tx);
    float ly = (py - r.ty) * (py - r.ty);
    float lw = (v2 - r.tw) * (v2 - r.tw);
    float lh = (v3 - r.th) * (v3 - r.th);
    float bce_obj = -logf(pconf);
    // class CE: log_softmax over sigmoid(class logits)
    float c[NC];
    float m = -INFINITY;
    for (int k = 0; k < NC; ++k) {
        float sv = sigmoidf_(x[base + (size_t)(7 + k) * CH]);
        c[k] = sv;
        m = fmaxf(m, sv);
    }
    float se = 0.0f;
    for (int k = 0; k < NC; ++k) se += expf(c[k] - m);
    float lse = m + logf(se);
    float ce = lse - c[r.label];
    atomicAdd(&acc[0], 1.0);
    atomicAdd(&acc[1], (double)lx);
    atomicAdd(&acc[2], (double)ly);
    atomicAdd(&acc[3], (double)lw);
    atomicAdd(&acc[4], (double)lh);
    atomicAdd(&acc[5], (double)bce_obj);
    atomicAdd(&acc[6], (double)ce);
}

// Phase C: dense noobj BCE over all B*nA*nH*nW cells; float4-vectorized conf-channel read.
__global__ void conf_pass_k(const float* __restrict__ x,
                            const unsigned char* __restrict__ flags,
                            double* __restrict__ acc) {
    const size_t CH = (size_t)NH * NW;
    const int N4 = (BB * NA * NH * NW) / 4;
    double s_bce = 0.0, s_cnt = 0.0;
    for (int n4 = blockIdx.x * blockDim.x + threadIdx.x; n4 < N4;
         n4 += gridDim.x * blockDim.x) {
        int n = n4 * 4;
        int b = n / (NA * NH * NW);
        int rr = n % (NA * NH * NW);
        int a = rr / (NH * NW);
        int hw = rr % (NH * NW);
        size_t xi = ((size_t)(b * NA + a) * ATTRS + 6) * CH + hw;
        float4 v = *reinterpret_cast<const float4*>(x + xi);
        uchar4 f = *reinterpret_cast<const uchar4*>(flags + n);
        float vv[4] = {v.x, v.y, v.z, v.w};
        unsigned char ff[4] = {f.x, f.y, f.z, f.w};
        #pragma unroll
        for (int e = 0; e < 4; ++e) {
            if (ff[e]) continue;  // mask cell (noobj=0) or conf-zeroed (conf_mask=0)
            float p = sigmoidf_(vv[e]);
            p = fminf(fmaxf(p, 1e-7f), 1.0f - 1e-7f);
            s_bce += (double)(-log1pf(-p));
            s_cnt += 1.0;
        }
    }
    // wave-64 reduction
    for (int off = 32; off > 0; off >>= 1) {
        s_bce += __shfl_down(s_bce, off);
        s_cnt += __shfl_down(s_cnt, off);
    }
    if ((threadIdx.x & 63) == 0) {
        atomicAdd(&acc[7], s_bce);
        atomicAdd(&acc[8], s_cnt);
    }
}

__global__ void finalize_k(const double* __restrict__ acc, float* __restrict__ out) {
    double n_obj = acc[0];
    double loss = (acc[1] + acc[2] + acc[3] + acc[4]) / n_obj    // x,y,w,h
                + acc[7] / acc[8]                                 // noobj conf
                + acc[5] / n_obj                                  // obj conf
                + (1.0 / (double)BB) * acc[6] / n_obj;            // cls
    out[0] = (float)loss;
}

extern "C" void kernel_launch(void* const* d_in, const int* in_sizes, int n_in,
                              void* d_out, int out_size, void* d_ws, size_t ws_size,
                              hipStream_t stream) {
    const float* x       = (const float*)d_in[0];
    const float* tgt     = (const float*)d_in[1];
    const float* anchors = (const float*)d_in[2];

    unsigned char* flags = (unsigned char*)d_ws;
    double* acc = (double*)((char*)d_ws + ACC_OFF);
    Rec* recs   = (Rec*)((char*)d_ws + REC_OFF);

    // zero flags + accumulators (ws is poisoned 0xAA before every timed call)
    hipMemsetAsync(d_ws, 0, REC_OFF, stream);

    build_targets_k<<<1, 64, 0, stream>>>(tgt, anchors, flags, recs);
    obj_losses_k<<<(BB * TT + 255) / 256, 256, 0, stream>>>(x, recs, acc);

    const int N4 = (BB * NA * NH * NW) / 4;   // 368,640
    int blocks = (N4 + 255) / 256;            // 1440
    conf_pass_k<<<blocks, 256, 0, stream>>>(x, flags, acc);

    finalize_k<<<1, 1, 0, stream>>>(acc, (float*)d_out);
}

// Round 4
// 146.028 us; speedup vs baseline: 1.8874x; 1.8874x over previous
//
#include <hip/hip_runtime.h>
#include <math.h>

#define BB 8
#define NA 5
#define NC 8
#define NH 192
#define NW 192
#define TT 50
#define ATTRS 15
#define THRESH_F 0.6f

#define NTGT (BB * TT)                     // 400
static const size_t FLAGS_N = (size_t)BB * NA * NH * NW;   // 1,474,560 bytes (u8 map)
#define ACC_OFF  FLAGS_N                   // 8B aligned
#define NACC 8                             // 0 n_obj, 1 sx, 2 sy, 3 sw, 4 sh, 5 bce_obj, 6 ce
#define PART_OFF (ACC_OFF + NACC * sizeof(double))
#define CONF_BLOCKS 1440

struct Rec {
    int cell;      // (a*NH + gj)*NW + gi  (within batch)
    int label;
    float tx, ty, tw, th;
    int valid;
    int pad;
};

__device__ __forceinline__ float sigmoidf_(float v) {
    return 1.0f / (1.0f + expf(-v));
}

// ---------------------------------------------------------------------------
// Kernel A: single block, 512 threads.
//   phase 1: one thread per (b,t) target -> Rec in LDS + atomicOr flag bits
//   phase 2: one thread per surviving target -> 7 loss terms, block-reduced,
//            written directly to acc[] (no global atomics, no acc memset).
// ---------------------------------------------------------------------------
__global__ __launch_bounds__(512) void build_obj_k(const float* __restrict__ x,
                                                   const float* __restrict__ tgt,
                                                   const float* __restrict__ anchors,
                                                   unsigned int* __restrict__ flags_w,
                                                   double* __restrict__ acc) {
    __shared__ Rec srecs[NTGT];
    __shared__ double wsum[8][8];   // [wave][value]
    const int tid = threadIdx.x;

    // ---- phase 1: build ----
    if (tid < NTGT) {
        const int b = tid / TT;
        const float* p = tgt + (size_t)tid * 5;
        float lab = p[0], cx = p[1], cy = p[2], cw = p[3], ch = p[4];
        int valid = ((lab + cx + cy + cw + ch) != 0.0f) ? 1 : 0;
        float gx = cx * NW, gy = cy * NH, gw = cw * NW, gh = ch * NH;
        int gi = min(max((int)floorf(gx), 0), NW - 1);
        int gj = min(max((int)floorf(gy), 0), NH - 1);
        float ious[NA];
        float aw[NA], ah[NA];
        int best = 0; float bi = -1.0f;
        #pragma unroll
        for (int a = 0; a < NA; ++a) {
            aw[a] = anchors[2 * a];
            ah[a] = anchors[2 * a + 1];
            float inter = fminf(gw, aw[a]) * fminf(gh, ah[a]);
            float un = gw * gh + aw[a] * ah[a] - inter;
            float iou = inter / un;
            ious[a] = iou;
            if (iou > bi) { bi = iou; best = a; }   // first-max (jnp.argmax)
        }
        if (valid) {
            #pragma unroll
            for (int a = 0; a < NA; ++a) {
                if (ious[a] > THRESH_F) {
                    size_t fi = (((size_t)b * NA + a) * NH + gj) * NW + gi;
                    atomicOr(&flags_w[fi >> 2], 1u << ((fi & 3) * 8));
                }
            }
            size_t fb = (((size_t)b * NA + best) * NH + gj) * NW + gi;
            atomicOr(&flags_w[fb >> 2], 2u << ((fb & 3) * 8));
        }
        Rec r;
        r.valid = valid;
        r.cell = (best * NH + gj) * NW + gi;
        r.label = (int)lab;
        r.tx = gx - floorf(gx);
        r.ty = gy - floorf(gy);
        r.tw = logf(gw / aw[best] + 1e-16f);
        r.th = logf(gh / ah[best] + 1e-16f);
        srecs[tid] = r;
    }
    __syncthreads();

    // ---- phase 2: per-object losses ----
    double v[7];
    #pragma unroll
    for (int k = 0; k < 7; ++k) v[k] = 0.0;

    if (tid < NTGT) {
        Rec r = srecs[tid];
        if (r.valid) {
            const int b = tid / TT, t = tid % TT;
            bool superseded = false;
            for (int t2 = t + 1; t2 < TT; ++t2) {
                Rec r2 = srecs[b * TT + t2];
                if (r2.valid && r2.cell == r.cell) { superseded = true; break; }
            }
            if (!superseded) {
                const size_t CH = (size_t)NH * NW;
                int a  = r.cell / (NH * NW);
                int hw = r.cell % (NH * NW);
                size_t base = ((size_t)(b * NA + a) * ATTRS) * CH + hw;
                float v0 = x[base + 0 * CH];
                float v1 = x[base + 1 * CH];
                float v2 = x[base + 2 * CH];
                float v3 = x[base + 3 * CH];
                float v6 = x[base + 6 * CH];
                float px = sigmoidf_(v0);
                float py = sigmoidf_(v1);
                float pconf = fminf(fmaxf(sigmoidf_(v6), 1e-7f), 1.0f - 1e-7f);
                float c[NC];
                float m = -INFINITY;
                #pragma unroll
                for (int k = 0; k < NC; ++k) {
                    float sv = sigmoidf_(x[base + (size_t)(7 + k) * CH]);
                    c[k] = sv;
                    m = fmaxf(m, sv);
                }
                float se = 0.0f;
                #pragma unroll
                for (int k = 0; k < NC; ++k) se += expf(c[k] - m);
                float lse = m + logf(se);
                v[0] = 1.0;
                v[1] = (double)((px - r.tx) * (px - r.tx));
                v[2] = (double)((py - r.ty) * (py - r.ty));
                v[3] = (double)((v2 - r.tw) * (v2 - r.tw));
                v[4] = (double)((v3 - r.th) * (v3 - r.th));
                v[5] = (double)(-logf(pconf));
                v[6] = (double)(lse - c[r.label]);
            }
        }
    }

    // ---- block reduce: 8 waves -> LDS -> thread 0 ----
    #pragma unroll
    for (int k = 0; k < 7; ++k)
        for (int off = 32; off > 0; off >>= 1)
            v[k] += __shfl_down(v[k], off);
    const int lane = tid & 63, wid = tid >> 6;
    if (lane == 0) {
        #pragma unroll
        for (int k = 0; k < 7; ++k) wsum[wid][k] = v[k];
    }
    __syncthreads();
    if (tid == 0) {
        #pragma unroll
        for (int k = 0; k < 7; ++k) {
            double s = 0.0;
            #pragma unroll
            for (int w = 0; w < 8; ++w) s += wsum[w][k];
            acc[k] = s;
        }
    }
}

// ---------------------------------------------------------------------------
// Kernel B: dense noobj BCE. Per-block LDS reduction -> partials[] (no atomics).
// ---------------------------------------------------------------------------
__global__ __launch_bounds__(256) void conf_pass_k(const float* __restrict__ x,
                                                   const unsigned char* __restrict__ flags,
                                                   double* __restrict__ partials) {
    __shared__ double wsum[4][2];
    const size_t CH = (size_t)NH * NW;
    const int N4 = (BB * NA * NH * NW) / 4;
    double s_bce = 0.0;
    float s_cnt = 0.0f;
    for (int n4 = blockIdx.x * blockDim.x + threadIdx.x; n4 < N4;
         n4 += gridDim.x * blockDim.x) {
        int n = n4 * 4;
        int b = n / (NA * NH * NW);
        int rr = n % (NA * NH * NW);
        int a = rr / (NH * NW);
        int hw = rr % (NH * NW);
        size_t xi = ((size_t)(b * NA + a) * ATTRS + 6) * CH + hw;
        float4 v = *reinterpret_cast<const float4*>(x + xi);
        uchar4 f = *reinterpret_cast<const uchar4*>(flags + n);
        float vv[4] = {v.x, v.y, v.z, v.w};
        unsigned char ff[4] = {f.x, f.y, f.z, f.w};
        #pragma unroll
        for (int e = 0; e < 4; ++e) {
            if (ff[e]) continue;           // mask cell or conf-zeroed cell -> noobj=0
            float p = fminf(fmaxf(sigmoidf_(vv[e]), 1e-7f), 1.0f - 1e-7f);
            s_bce += (double)(-log1pf(-p));
            s_cnt += 1.0f;
        }
    }
    double s_cd = (double)s_cnt;
    for (int off = 32; off > 0; off >>= 1) {
        s_bce += __shfl_down(s_bce, off);
        s_cd  += __shfl_down(s_cd, off);
    }
    const int lane = threadIdx.x & 63, wid = threadIdx.x >> 6;
    if (lane == 0) { wsum[wid][0] = s_bce; wsum[wid][1] = s_cd; }
    __syncthreads();
    if (threadIdx.x == 0) {
        double b0 = 0.0, c0 = 0.0;
        #pragma unroll
        for (int w = 0; w < 4; ++w) { b0 += wsum[w][0]; c0 += wsum[w][1]; }
        partials[2 * blockIdx.x]     = b0;
        partials[2 * blockIdx.x + 1] = c0;
    }
}

// ---------------------------------------------------------------------------
// Kernel C: sum block partials + combine with acc -> scalar loss.
// ---------------------------------------------------------------------------
__global__ __launch_bounds__(256) void finalize_k(const double* __restrict__ acc,
                                                  const double* __restrict__ partials,
                                                  float* __restrict__ out) {
    __shared__ double wsum[4][2];
    double sb = 0.0, sc = 0.0;
    for (int i = threadIdx.x; i < CONF_BLOCKS; i += 256) {
        sb += partials[2 * i];
        sc += partials[2 * i + 1];
    }
    for (int off = 32; off > 0; off >>= 1) {
        sb += __shfl_down(sb, off);
        sc += __shfl_down(sc, off);
    }
    const int lane = threadIdx.x & 63, wid = threadIdx.x >> 6;
    if (lane == 0) { wsum[wid][0] = sb; wsum[wid][1] = sc; }
    __syncthreads();
    if (threadIdx.x == 0) {
        double b0 = 0.0, c0 = 0.0;
        #pragma unroll
        for (int w = 0; w < 4; ++w) { b0 += wsum[w][0]; c0 += wsum[w][1]; }
        double n_obj = acc[0];
        double loss = (acc[1] + acc[2] + acc[3] + acc[4]) / n_obj   // x,y,w,h
                    + b0 / c0                                       // noobj conf
                    + acc[5] / n_obj                                // obj conf
                    + (1.0 / (double)BB) * acc[6] / n_obj;          // cls
        out[0] = (float)loss;
    }
}

extern "C" void kernel_launch(void* const* d_in, const int* in_sizes, int n_in,
                              void* d_out, int out_size, void* d_ws, size_t ws_size,
                              hipStream_t stream) {
    const float* x       = (const float*)d_in[0];
    const float* tgt     = (const float*)d_in[1];
    const float* anchors = (const float*)d_in[2];

    unsigned int* flags_w = (unsigned int*)d_ws;
    unsigned char* flags  = (unsigned char*)d_ws;
    double* acc      = (double*)((char*)d_ws + ACC_OFF);
    double* partials = (double*)((char*)d_ws + PART_OFF);

    // only the flag map needs zeroing (acc/partials are fully written)
    hipMemsetAsync(d_ws, 0, FLAGS_N, stream);

    build_obj_k<<<1, 512, 0, stream>>>(x, tgt, anchors, flags_w, acc);
    conf_pass_k<<<CONF_BLOCKS, 256, 0, stream>>>(x, flags, partials);
    finalize_k<<<1, 256, 0, stream>>>(acc, partials, (float*)d_out);
}